// Round 12
// baseline (147.122 us; speedup 1.0000x reference)
//
#include <hip/hip_runtime.h>

typedef unsigned long long ull;
typedef float f4 __attribute__((ext_vector_type(4)));

#define TOKENS 2048
#define KNN    32
#define VOCAB  32000
#define CAP    512

// u64 sorted-descending 8-slot insert (c0..c7)
#define INSK(key) do {                                                       \
    ull k_ = (key);                                                          \
    if (k_ > c7) {                                                           \
        ull tmp_;                                                            \
        if (k_ > c0) { tmp_ = c0; c0 = k_; k_ = tmp_; }                      \
        if (k_ > c1) { tmp_ = c1; c1 = k_; k_ = tmp_; }                      \
        if (k_ > c2) { tmp_ = c2; c2 = k_; k_ = tmp_; }                      \
        if (k_ > c3) { tmp_ = c3; c3 = k_; k_ = tmp_; }                      \
        if (k_ > c4) { tmp_ = c4; c4 = k_; k_ = tmp_; }                      \
        if (k_ > c5) { tmp_ = c5; c5 = k_; k_ = tmp_; }                      \
        if (k_ > c6) { tmp_ = c6; c6 = k_; k_ = tmp_; }                      \
        c7 = (k_ > c7) ? k_ : c7;                                            \
    }                                                                        \
} while (0)

// branch-free sorted-descending 8-float insert (fallback path only)
#define INSF(vv) do {                                                        \
    float x_ = (vv);                                                         \
    if (x_ > t7) {                                                           \
        float h_;                                                            \
        h_ = fmaxf(t0, x_); x_ = fminf(t0, x_); t0 = h_;                     \
        h_ = fmaxf(t1, x_); x_ = fminf(t1, x_); t1 = h_;                     \
        h_ = fmaxf(t2, x_); x_ = fminf(t2, x_); t2 = h_;                     \
        h_ = fmaxf(t3, x_); x_ = fminf(t3, x_); t3 = h_;                     \
        h_ = fmaxf(t4, x_); x_ = fminf(t4, x_); t4 = h_;                     \
        h_ = fmaxf(t5, x_); x_ = fminf(t5, x_); t5 = h_;                     \
        h_ = fmaxf(t6, x_); x_ = fminf(t6, x_); t6 = h_;                     \
        t7 = fmaxf(t7, x_);                                                  \
    }                                                                        \
} while (0)

#define MAX4(v_) fmaxf(fmaxf(v_.x, v_.y), fmaxf(v_.z, v_.w))

#define COLLECT(v_) do {                                                     \
    if (v_.x >= T) { int p = atomicAdd(&s_n, 1); if (p < CAP) s_cand[p] = v_.x; } \
    if (v_.y >= T) { int p = atomicAdd(&s_n, 1); if (p < CAP) s_cand[p] = v_.y; } \
    if (v_.z >= T) { int p = atomicAdd(&s_n, 1); if (p < CAP) s_cand[p] = v_.z; } \
    if (v_.w >= T) { int p = atomicAdd(&s_n, 1); if (p < CAP) s_cand[p] = v_.w; } \
} while (0)

// batch of 8 pure loads -> fmax tree (no stores in this kernel at all)
#define BATCH8(kb) do {                                                      \
    f4 v0 = np4[tid + (((kb)+0) << 8)];                                      \
    f4 v1 = np4[tid + (((kb)+1) << 8)];                                      \
    f4 v2 = np4[tid + (((kb)+2) << 8)];                                      \
    f4 v3 = np4[tid + (((kb)+3) << 8)];                                      \
    f4 v4 = np4[tid + (((kb)+4) << 8)];                                      \
    f4 v5 = np4[tid + (((kb)+5) << 8)];                                      \
    f4 v6 = np4[tid + (((kb)+6) << 8)];                                      \
    f4 v7 = np4[tid + (((kb)+7) << 8)];                                      \
    float m01 = fmaxf(MAX4(v0), MAX4(v1));                                   \
    float m23 = fmaxf(MAX4(v2), MAX4(v3));                                   \
    float m45 = fmaxf(MAX4(v4), MAX4(v5));                                   \
    float m67 = fmaxf(MAX4(v6), MAX4(v7));                                   \
    m = fmaxf(m, fmaxf(fmaxf(m01, m23), fmaxf(m45, m67)));                   \
} while (0)

// ---------------- K_scan: PURE READ. top-8 values per token -> ws ----------------
__global__ __launch_bounds__(256, 8)
void k_scan(const float* __restrict__ net_probs, float* __restrict__ ws)
{
    const int t   = blockIdx.x;
    const int tid = threadIdx.x;

    __shared__ float s_max[256];
    __shared__ float s_cand[CAP];
    __shared__ int   s_n;
    __shared__ float s_thr;
    __shared__ float s_top8[8];

    if (tid == 0) s_n = 0;

    const f4* np4 = (const f4*)(net_probs + (size_t)t * VOCAB);

    // pass 1: branch-free stripe max (8000 f4: k=0..30 all threads, k=31 tid<64)
    float m = 0.f;
    BATCH8(0);
    BATCH8(8);
    BATCH8(16);
    {   // k = 24..30
        f4 v0 = np4[tid + (24 << 8)];
        f4 v1 = np4[tid + (25 << 8)];
        f4 v2 = np4[tid + (26 << 8)];
        f4 v3 = np4[tid + (27 << 8)];
        f4 v4 = np4[tid + (28 << 8)];
        f4 v5 = np4[tid + (29 << 8)];
        f4 v6 = np4[tid + (30 << 8)];
        float m01 = fmaxf(MAX4(v0), MAX4(v1));
        float m23 = fmaxf(MAX4(v2), MAX4(v3));
        float m45 = fmaxf(MAX4(v4), MAX4(v5));
        m = fmaxf(m, fmaxf(fmaxf(m01, m23), fmaxf(m45, MAX4(v6))));
    }
    if (tid < 64) {
        f4 v = np4[tid + (31 << 8)];
        m = fmaxf(m, MAX4(v));
    }
    s_max[tid] = m;
    __syncthreads();

    // threshold: T = 8th largest of the 256 stripe maxes (one wave)
    if (tid < 64) {
        ull c0 = 0, c1 = 0, c2 = 0, c3 = 0, c4 = 0, c5 = 0, c6 = 0, c7 = 0;
        #pragma unroll
        for (int k = 0; k < 4; ++k) {
            int idx = tid + (k << 6);
            ull key = (((ull)__float_as_uint(s_max[idx])) << 32) | (unsigned)idx;
            INSK(key);
        }
        ull g = 0;
        for (int r = 0; r < 8; ++r) {
            g = c0;
            #pragma unroll
            for (int off = 1; off < 64; off <<= 1) {
                ull o = __shfl_xor(g, off);
                if (o > g) g = o;
            }
            if (c0 == g) {
                c0 = c1; c1 = c2; c2 = c3; c3 = c4; c4 = c5; c5 = c6; c6 = c7; c7 = 0;
            }
        }
        if (tid == 0) s_thr = __uint_as_float((unsigned)(g >> 32));
    }
    __syncthreads();
    const float T = s_thr;

    // pass 2: selective re-scan — only qualifying stripes (~8/256), L2/L3-hot
    if (m >= T) {
        for (int k = 0; k < 31; ++k) {
            f4 v = np4[tid + (k << 8)];
            COLLECT(v);
        }
        if (tid < 64) {
            f4 v = np4[tid + (31 << 8)];
            COLLECT(v);
        }
    }
    __syncthreads();
    const int n = s_n;

    if (n <= CAP) {
        if (tid < 64) {
            ull c0 = 0, c1 = 0, c2 = 0, c3 = 0, c4 = 0, c5 = 0, c6 = 0, c7 = 0;
            for (int i = tid; i < n; i += 64) {
                ull key = (((ull)__float_as_uint(s_cand[i])) << 32) | (unsigned)i;
                INSK(key);
            }
            for (int r = 0; r < 8; ++r) {
                ull g = c0;
                #pragma unroll
                for (int off = 1; off < 64; off <<= 1) {
                    ull o = __shfl_xor(g, off);
                    if (o > g) g = o;
                }
                if (c0 == g && g != 0ULL) {
                    c0 = c1; c1 = c2; c2 = c3; c3 = c4; c4 = c5; c5 = c6; c6 = c7; c7 = 0;
                }
                if (tid == 0) s_top8[r] = __uint_as_float((unsigned)(g >> 32));
            }
        }
    } else {
        // fallback (adversarial ties): per-thread exact top-8 + full merge via s_max reuse
        float t0 = 0.f, t1 = 0.f, t2 = 0.f, t3 = 0.f,
              t4 = 0.f, t5 = 0.f, t6 = 0.f, t7 = 0.f;
        for (int k = 0; k < 31; ++k) {
            f4 v = np4[tid + (k << 8)];
            if (MAX4(v) > t7) { INSF(v.x); INSF(v.y); INSF(v.z); INSF(v.w); }
        }
        if (tid < 64) {
            f4 v = np4[tid + (31 << 8)];
            if (MAX4(v) > t7) { INSF(v.x); INSF(v.y); INSF(v.z); INSF(v.w); }
        }
        // 8 extraction rounds over the 2048 per-thread values, via block max in s_max
        for (int r = 0; r < 8; ++r) {
            s_max[tid] = t0;
            __syncthreads();
            if (tid < 64) {
                float g = s_max[tid];
                g = fmaxf(g, s_max[tid + 64]);
                g = fmaxf(g, s_max[tid + 128]);
                g = fmaxf(g, s_max[tid + 192]);
                #pragma unroll
                for (int off = 1; off < 64; off <<= 1)
                    g = fmaxf(g, __shfl_xor(g, off));
                if (tid == 0) { s_thr = g; s_top8[r] = g; }
            }
            __syncthreads();
            // exactly-one pop: the first thread holding the max pops (resolve via ballot)
            float g = s_thr;
            ull mask = __ballot(t0 == g);   // 64-bit per wave; need block-unique -> use LDS turn
            // block-level unique pop: lowest tid with t0==g pops
            __shared__ int s_win;
            if (tid == 0) s_win = 0x7fffffff;
            __syncthreads();
            if (t0 == g) atomicMin(&s_win, tid);
            __syncthreads();
            if (tid == s_win) {
                t0 = t1; t1 = t2; t2 = t3; t3 = t4; t4 = t5; t5 = t6; t6 = t7; t7 = 0.f;
            }
            __syncthreads();
            (void)mask;
        }
    }
    __syncthreads();

    if (tid < 8) ws[(size_t)t * 8 + tid] = s_top8[tid];
}

// ---------------- K_zero: PURE WRITE. zero the token's output row ----------------
__global__ __launch_bounds__(256, 8)
void k_zero(float* __restrict__ out)
{
    const int t   = blockIdx.x;
    const int tid = threadIdx.x;
    f4*      o4 = (f4*)(out + (size_t)t * VOCAB);
    const f4 z4 = (f4){0.f, 0.f, 0.f, 0.f};
    #pragma unroll
    for (int k = 0; k < 31; ++k) o4[tid + (k << 8)] = z4;
    if (tid < 64) o4[tid + (31 << 8)] = z4;
}

// ---------------- K2: tiny math + scatter ----------------
__global__ __launch_bounds__(256, 8)
void k2_final(const int*   __restrict__ tgt_index,
              const float* __restrict__ knn_dists,
              const float* __restrict__ knn_key,
              const float* __restrict__ net_sel,
              const float* __restrict__ W_func, const float* __restrict__ b_func,
              const float* __restrict__ W1a,    const float* __restrict__ b1a,
              const float* __restrict__ W1b,    const float* __restrict__ b1b,
              const float* __restrict__ W2a,    const float* __restrict__ b2a,
              const float* __restrict__ W2b,    const float* __restrict__ b2b,
              const float* __restrict__ ws,
              float* __restrict__ out)
{
    const int t   = blockIdx.x;
    const int tid = threadIdx.x;

    __shared__ int   s_tgt[KNN];
    __shared__ float s_dist[KNN];
    __shared__ float s_cnt[KNN];
    __shared__ float s_top8[8];

    int   tg = 0;
    float d = 0.f, lk = 0.f, ls = 0.f;
    if (tid < KNN) {
        tg = tgt_index[t * KNN + tid];
        d  = knn_dists[t * KNN + tid];
        lk = logf(knn_key[t * KNN + tid]);
        ls = logf(net_sel[t * KNN + tid]);
        s_tgt[tid]  = tg;
        s_dist[tid] = d;
    }
    if (tid < 8) s_top8[tid] = ws[(size_t)t * 8 + tid];
    __syncthreads();

    // label counts (distinct, reference never counts label 0)
    if (tid < KNN) {
        int fo = (tg != 0) ? 1 : 0;
        if (fo) {
            for (int j = 0; j < tid; ++j)
                if (s_tgt[j] == tg) { fo = 0; break; }
        }
        int c = fo;
        #pragma unroll
        for (int off = 1; off < KNN; off <<= 1) {
            int n2 = __shfl_up(c, off, KNN);
            if (tid >= off) c += n2;
        }
        s_cnt[tid] = (float)c;
    }
    __syncthreads();

    if (tid < KNN) {
        // noise_logit: Linear(2,4) -> tanh -> Linear(4,1)
        float noise = b1b[0];
        #pragma unroll
        for (int j = 0; j < 4; ++j) {
            float z = tanhf(W1a[2 * j] * lk + W1a[2 * j + 1] * ls + b1a[j]);
            noise += W1b[j] * z;
        }

        // sim_lambda = W_func . [log(top8) | log_key | log_sel] + b_func
        float sp = W_func[8 + tid] * lk + W_func[40 + tid] * ls;
        if (tid < 8) sp += W_func[tid] * logf(s_top8[tid]);
        #pragma unroll
        for (int off = 16; off; off >>= 1) sp += __shfl_xor(sp, off, KNN);
        float sim = sp + b_func[0];

        // lambda_logit: Linear(64,32) -> tanh -> Linear(32,2); lane = hidden unit
        float h = b2a[tid];
        const float* wr = W2a + tid * 64;
        #pragma unroll 8
        for (int i = 0; i < KNN; ++i) h += wr[i] * s_dist[i];
        #pragma unroll 8
        for (int i = 0; i < KNN; ++i) h += wr[KNN + i] * s_cnt[i];
        h = tanhf(h);
        float p0 = W2b[tid] * h;
        float p1 = W2b[KNN + tid] * h;
        #pragma unroll
        for (int off = 16; off; off >>= 1) {
            p0 += __shfl_xor(p0, off, KNN);
            p1 += __shfl_xor(p1, off, KNN);
        }
        float l0 = p0 + b2b[0];
        float l1 = p1 + b2b[1];

        float tempe = 1.f / (1.f + expf(-l1));          // sigmoid(l1)
        float lam   = 1.f / (1.f + expf(-(l0 - sim)));  // softmax([l0,sim])[0]

        // probs = softmax(-d*tempe + noise) over K
        float logit = -d * tempe + noise;
        float mx = logit;
        #pragma unroll
        for (int off = 16; off; off >>= 1) mx = fmaxf(mx, __shfl_xor(mx, off, KNN));
        float e = expf(logit - mx);
        float se = e;
        #pragma unroll
        for (int off = 16; off; off >>= 1) se += __shfl_xor(se, off, KNN);
        float p = e / se;

        // scatter, last-occurrence-wins on duplicate indices (numpy semantics)
        bool wrte = true;
        for (int j = tid + 1; j < KNN; ++j)
            if (s_tgt[j] == tg) { wrte = false; break; }
        if (wrte) out[(size_t)t * VOCAB + tg] = p;

        if (tid == 0) out[(size_t)TOKENS * VOCAB + t] = lam;
    }
}

extern "C" void kernel_launch(void* const* d_in, const int* in_sizes, int n_in,
                              void* d_out, int out_size, void* d_ws, size_t ws_size,
                              hipStream_t stream) {
    float* ws = (float*)d_ws;   // TOKENS*8*4 = 64 KB

    // pure read stream
    k_scan<<<TOKENS, 256, 0, stream>>>((const float*)d_in[3], ws);
    // pure write stream
    k_zero<<<TOKENS, 256, 0, stream>>>((float*)d_out);
    // tiny epilogue
    k2_final<<<TOKENS, 256, 0, stream>>>(
        (const int*)  d_in[0],   // tgt_index
        (const float*)d_in[1],   // knn_dists
        (const float*)d_in[2],   // knn_key_feature
        (const float*)d_in[4],   // network_select_probs
        (const float*)d_in[5],  (const float*)d_in[6],   // W_func, b_func
        (const float*)d_in[7],  (const float*)d_in[8],   // W1a, b1a
        (const float*)d_in[9],  (const float*)d_in[10],  // W1b, b1b
        (const float*)d_in[11], (const float*)d_in[12],  // W2a, b2a
        (const float*)d_in[13], (const float*)d_in[14],  // W2b, b2b
        ws,
        (float*)d_out);
}

// Round 13
// 137.651 us; speedup vs baseline: 1.0688x; 1.0688x over previous
//
#include <hip/hip_runtime.h>

typedef unsigned long long ull;
typedef float f4 __attribute__((ext_vector_type(4)));

#define TOKENS 2048
#define KNN    32
#define VOCAB  32000
#define NB_STREAM 2000
#define NT_STREAM (NB_STREAM * 256)       // 512000 threads
#define ITER      32                       // 16,384,000 f4 / 512,000
#define NWAVE     (NT_STREAM / 64)         // 8000 waves
#define SEG_PER_TOK 125                    // 8000 f4 per token / 64
#define CAP    2048

#define MAX4(v_) fmaxf(fmaxf(v_.x, v_.y), fmaxf(v_.z, v_.w))

// u64 sorted-descending 8-slot insert (c0..c7)
#define INSK(key) do {                                                       \
    ull k_ = (key);                                                          \
    if (k_ > c7) {                                                           \
        ull tmp_;                                                            \
        if (k_ > c0) { tmp_ = c0; c0 = k_; k_ = tmp_; }                      \
        if (k_ > c1) { tmp_ = c1; c1 = k_; k_ = tmp_; }                      \
        if (k_ > c2) { tmp_ = c2; c2 = k_; k_ = tmp_; }                      \
        if (k_ > c3) { tmp_ = c3; c3 = k_; k_ = tmp_; }                      \
        if (k_ > c4) { tmp_ = c4; c4 = k_; k_ = tmp_; }                      \
        if (k_ > c5) { tmp_ = c5; c5 = k_; k_ = tmp_; }                      \
        if (k_ > c6) { tmp_ = c6; c6 = k_; k_ = tmp_; }                      \
        c7 = (k_ > c7) ? k_ : c7;                                            \
    }                                                                        \
} while (0)

// branch-free sorted-descending 8-float insert (fallback path only)
#define INSF(vv) do {                                                        \
    float x_ = (vv);                                                         \
    if (x_ > t7) {                                                           \
        float h_;                                                            \
        h_ = fmaxf(t0, x_); x_ = fminf(t0, x_); t0 = h_;                     \
        h_ = fmaxf(t1, x_); x_ = fminf(t1, x_); t1 = h_;                     \
        h_ = fmaxf(t2, x_); x_ = fminf(t2, x_); t2 = h_;                     \
        h_ = fmaxf(t3, x_); x_ = fminf(t3, x_); t3 = h_;                     \
        h_ = fmaxf(t4, x_); x_ = fminf(t4, x_); t4 = h_;                     \
        h_ = fmaxf(t5, x_); x_ = fminf(t5, x_); t5 = h_;                     \
        h_ = fmaxf(t6, x_); x_ = fminf(t6, x_); t6 = h_;                     \
        t7 = fmaxf(t7, x_);                                                  \
    }                                                                        \
} while (0)

#define COLLECT(v_) do {                                                     \
    if (v_.x >= T) { int p = atomicAdd(&s_n, 1); if (p < CAP) s_cand[p] = v_.x; } \
    if (v_.y >= T) { int p = atomicAdd(&s_n, 1); if (p < CAP) s_cand[p] = v_.y; } \
    if (v_.z >= T) { int p = atomicAdd(&s_n, 1); if (p < CAP) s_cand[p] = v_.z; } \
    if (v_.w >= T) { int p = atomicAdd(&s_n, 1); if (p < CAP) s_cand[p] = v_.w; } \
} while (0)

// ---------- K1: DENSE grid-stride read sweep -> per-64-f4-segment max ----------
__global__ __launch_bounds__(256, 8)
void k1_segmax(const float* __restrict__ net_probs, float* __restrict__ ws)
{
    const int g = blockIdx.x * 256 + threadIdx.x;
    const int w = g >> 6;                        // global wave id (0..7999)
    const f4* np4 = (const f4*)net_probs;
    #pragma unroll 4
    for (int i = 0; i < ITER; ++i) {
        f4 v = np4[(size_t)g + (size_t)i * NT_STREAM];
        float m = MAX4(v);
        #pragma unroll
        for (int off = 32; off; off >>= 1) m = fmaxf(m, __shfl_xor(m, off));
        if ((threadIdx.x & 63) == 0) ws[w + i * NWAVE] = m;
    }
}

// ---------- K_zero: DENSE grid-stride pure-write zero sweep ----------
__global__ __launch_bounds__(256, 8)
void k_zero(float* __restrict__ out)
{
    const int g = blockIdx.x * 256 + threadIdx.x;
    f4* o4 = (f4*)out;
    const f4 z4 = (f4){0.f, 0.f, 0.f, 0.f};
    #pragma unroll 8
    for (int i = 0; i < ITER; ++i)
        o4[(size_t)g + (size_t)i * NT_STREAM] = z4;
}

// ---------- K2: per-token threshold + selective re-read + math + scatter ----------
__global__ __launch_bounds__(256, 8)
void k2_final(const int*   __restrict__ tgt_index,
              const float* __restrict__ knn_dists,
              const float* __restrict__ knn_key,
              const float* __restrict__ net_probs,
              const float* __restrict__ net_sel,
              const float* __restrict__ W_func, const float* __restrict__ b_func,
              const float* __restrict__ W1a,    const float* __restrict__ b1a,
              const float* __restrict__ W1b,    const float* __restrict__ b1b,
              const float* __restrict__ W2a,    const float* __restrict__ b2a,
              const float* __restrict__ W2b,    const float* __restrict__ b2b,
              const float* __restrict__ ws,
              float* __restrict__ out)
{
    const int t   = blockIdx.x;
    const int tid = threadIdx.x;

    __shared__ float s_sm[128];     // 125 segment maxes (padded with 0)
    __shared__ int   s_qseg[128];
    __shared__ int   s_nq;
    __shared__ float s_thr;
    __shared__ float s_cand[CAP];
    __shared__ int   s_n;
    __shared__ float s_red[256];
    __shared__ int   s_win;
    __shared__ int   s_tgt[KNN];
    __shared__ float s_dist[KNN];
    __shared__ float s_cnt[KNN];
    __shared__ float s_top8[8];

    if (tid == 0) { s_nq = 0; s_n = 0; }

    int   tg = 0;
    float d = 0.f, lk = 0.f, ls = 0.f;
    if (tid < KNN) {
        tg = tgt_index[t * KNN + tid];
        d  = knn_dists[t * KNN + tid];
        lk = logf(knn_key[t * KNN + tid]);
        ls = logf(net_sel[t * KNN + tid]);
        s_tgt[tid]  = tg;
        s_dist[tid] = d;
    }
    if (tid < 128) s_sm[tid] = (tid < SEG_PER_TOK) ? ws[t * SEG_PER_TOK + tid] : 0.f;
    __syncthreads();

    // T = 8th largest segment max (one wave, 2 keys/lane over 128 slots)
    if (tid < 64) {
        ull c0 = 0, c1 = 0, c2 = 0, c3 = 0, c4 = 0, c5 = 0, c6 = 0, c7 = 0;
        ull k0 = (((ull)__float_as_uint(s_sm[tid])) << 32) | (unsigned)tid;
        INSK(k0);
        ull k1 = (((ull)__float_as_uint(s_sm[tid + 64])) << 32) | (unsigned)(tid + 64);
        INSK(k1);
        ull g = 0;
        for (int r = 0; r < 8; ++r) {
            g = c0;
            #pragma unroll
            for (int off = 1; off < 64; off <<= 1) {
                ull o = __shfl_xor(g, off);
                if (o > g) g = o;
            }
            if (c0 == g) {
                c0 = c1; c1 = c2; c2 = c3; c3 = c4; c4 = c5; c5 = c6; c6 = c7; c7 = 0;
            }
        }
        if (tid == 0) s_thr = __uint_as_float((unsigned)(g >> 32));
    }
    __syncthreads();
    const float T = s_thr;

    // qualifying segments (~8 of 125)
    if (tid < SEG_PER_TOK && s_sm[tid] >= T) {
        int p = atomicAdd(&s_nq, 1);
        s_qseg[p] = tid;
    }
    __syncthreads();
    const int nq = s_nq;

    // selective re-read: one wave per qualifying segment (64 f4 = 1 KB each)
    const f4* np4 = (const f4*)(net_probs + (size_t)t * VOCAB);
    for (int base = 0; base < nq; base += 4) {
        int qi = base + (tid >> 6);
        if (qi < nq) {
            int seg = s_qseg[qi];
            f4 v = np4[seg * 64 + (tid & 63)];
            COLLECT(v);
        }
    }
    __syncthreads();
    const int n = s_n;

    if (n <= CAP) {
        if (tid < 64) {
            ull c0 = 0, c1 = 0, c2 = 0, c3 = 0, c4 = 0, c5 = 0, c6 = 0, c7 = 0;
            for (int i = tid; i < n; i += 64) {
                ull key = (((ull)__float_as_uint(s_cand[i])) << 32) | (unsigned)i;
                INSK(key);
            }
            for (int r = 0; r < 8; ++r) {
                ull g = c0;
                #pragma unroll
                for (int off = 1; off < 64; off <<= 1) {
                    ull o = __shfl_xor(g, off);
                    if (o > g) g = o;
                }
                if (c0 == g && g != 0ULL) {
                    c0 = c1; c1 = c2; c2 = c3; c3 = c4; c4 = c5; c5 = c6; c6 = c7; c7 = 0;
                }
                if (tid == 0) s_top8[r] = __uint_as_float((unsigned)(g >> 32));
            }
        }
    } else {
        // fallback (adversarial ties): exact full-row per-thread top-8 + extraction
        float t0 = 0.f, t1 = 0.f, t2 = 0.f, t3 = 0.f,
              t4 = 0.f, t5 = 0.f, t6 = 0.f, t7 = 0.f;
        for (int k = 0; k < 31; ++k) {
            f4 v = np4[tid + (k << 8)];
            if (MAX4(v) > t7) { INSF(v.x); INSF(v.y); INSF(v.z); INSF(v.w); }
        }
        if (tid < 64) {
            f4 v = np4[tid + (31 << 8)];
            if (MAX4(v) > t7) { INSF(v.x); INSF(v.y); INSF(v.z); INSF(v.w); }
        }
        for (int r = 0; r < 8; ++r) {
            s_red[tid] = t0;
            __syncthreads();
            if (tid < 64) {
                float g = s_red[tid];
                g = fmaxf(g, s_red[tid + 64]);
                g = fmaxf(g, s_red[tid + 128]);
                g = fmaxf(g, s_red[tid + 192]);
                #pragma unroll
                for (int off = 1; off < 64; off <<= 1)
                    g = fmaxf(g, __shfl_xor(g, off));
                if (tid == 0) { s_thr = g; s_top8[r] = g; }
            }
            if (tid == 0) s_win = 0x7fffffff;
            __syncthreads();
            if (t0 == s_thr) atomicMin(&s_win, tid);
            __syncthreads();
            if (tid == s_win) {
                t0 = t1; t1 = t2; t2 = t3; t3 = t4; t4 = t5; t5 = t6; t6 = t7; t7 = 0.f;
            }
            __syncthreads();
        }
    }
    __syncthreads();

    // label counts (distinct, reference never counts label 0)
    if (tid < KNN) {
        int fo = (tg != 0) ? 1 : 0;
        if (fo) {
            for (int j = 0; j < tid; ++j)
                if (s_tgt[j] == tg) { fo = 0; break; }
        }
        int c = fo;
        #pragma unroll
        for (int off = 1; off < KNN; off <<= 1) {
            int n2 = __shfl_up(c, off, KNN);
            if (tid >= off) c += n2;
        }
        s_cnt[tid] = (float)c;
    }
    __syncthreads();

    if (tid < KNN) {
        // noise_logit: Linear(2,4) -> tanh -> Linear(4,1)
        float noise = b1b[0];
        #pragma unroll
        for (int j = 0; j < 4; ++j) {
            float z = tanhf(W1a[2 * j] * lk + W1a[2 * j + 1] * ls + b1a[j]);
            noise += W1b[j] * z;
        }

        // sim_lambda = W_func . [log(top8) | log_key | log_sel] + b_func
        float sp = W_func[8 + tid] * lk + W_func[40 + tid] * ls;
        if (tid < 8) sp += W_func[tid] * logf(s_top8[tid]);
        #pragma unroll
        for (int off = 16; off; off >>= 1) sp += __shfl_xor(sp, off, KNN);
        float sim = sp + b_func[0];

        // lambda_logit: Linear(64,32) -> tanh -> Linear(32,2); lane = hidden unit
        float h = b2a[tid];
        const float* wr = W2a + tid * 64;
        #pragma unroll 8
        for (int i = 0; i < KNN; ++i) h += wr[i] * s_dist[i];
        #pragma unroll 8
        for (int i = 0; i < KNN; ++i) h += wr[KNN + i] * s_cnt[i];
        h = tanhf(h);
        float p0 = W2b[tid] * h;
        float p1 = W2b[KNN + tid] * h;
        #pragma unroll
        for (int off = 16; off; off >>= 1) {
            p0 += __shfl_xor(p0, off, KNN);
            p1 += __shfl_xor(p1, off, KNN);
        }
        float l0 = p0 + b2b[0];
        float l1 = p1 + b2b[1];

        float tempe = 1.f / (1.f + expf(-l1));          // sigmoid(l1)
        float lam   = 1.f / (1.f + expf(-(l0 - sim)));  // softmax([l0,sim])[0]

        // probs = softmax(-d*tempe + noise) over K
        float logit = -d * tempe + noise;
        float mx = logit;
        #pragma unroll
        for (int off = 16; off; off >>= 1) mx = fmaxf(mx, __shfl_xor(mx, off, KNN));
        float e = expf(logit - mx);
        float se = e;
        #pragma unroll
        for (int off = 16; off; off >>= 1) se += __shfl_xor(se, off, KNN);
        float p = e / se;

        // scatter, last-occurrence-wins on duplicate indices (numpy semantics)
        bool wrte = true;
        for (int j = tid + 1; j < KNN; ++j)
            if (s_tgt[j] == tg) { wrte = false; break; }
        if (wrte) out[(size_t)t * VOCAB + tg] = p;

        if (tid == 0) out[(size_t)TOKENS * VOCAB + t] = lam;
    }
}

extern "C" void kernel_launch(void* const* d_in, const int* in_sizes, int n_in,
                              void* d_out, int out_size, void* d_ws, size_t ws_size,
                              hipStream_t stream) {
    float* ws = (float*)d_ws;   // 256,000 floats = 1 MB

    // dense read sweep -> segment maxes
    k1_segmax<<<NB_STREAM, 256, 0, stream>>>((const float*)d_in[3], ws);
    // dense write sweep -> zero output rows
    k_zero<<<NB_STREAM, 256, 0, stream>>>((float*)d_out);
    // per-token epilogue
    k2_final<<<TOKENS, 256, 0, stream>>>(
        (const int*)  d_in[0],   // tgt_index
        (const float*)d_in[1],   // knn_dists
        (const float*)d_in[2],   // knn_key_feature
        (const float*)d_in[3],   // network_probs
        (const float*)d_in[4],   // network_select_probs
        (const float*)d_in[5],  (const float*)d_in[6],   // W_func, b_func
        (const float*)d_in[7],  (const float*)d_in[8],   // W1a, b1a
        (const float*)d_in[9],  (const float*)d_in[10],  // W1b, b1b
        (const float*)d_in[11], (const float*)d_in[12],  // W2a, b2a
        (const float*)d_in[13], (const float*)d_in[14],  // W2b, b2b
        ws,
        (float*)d_out);
}

// Round 14
// 129.534 us; speedup vs baseline: 1.1358x; 1.0627x over previous
//
#include <hip/hip_runtime.h>

typedef unsigned long long ull;
typedef float f4 __attribute__((ext_vector_type(4)));

#define TOKENS 2048
#define KNN    32
#define VOCAB  32000
#define NB_STREAM 2000
#define NT_STREAM (NB_STREAM * 256)       // 512000 threads
#define ITER      32                       // 16,384,000 f4 / 512,000
#define NWAVE     (NT_STREAM / 64)         // 8000 waves
#define SEG_PER_TOK 125                    // 8000 f4 per token / 64
#define CAP    2048

#define MAX4(v_) fmaxf(fmaxf(v_.x, v_.y), fmaxf(v_.z, v_.w))

// u64 sorted-descending 8-slot insert (c0..c7)
#define INSK(key) do {                                                       \
    ull k_ = (key);                                                          \
    if (k_ > c7) {                                                           \
        ull tmp_;                                                            \
        if (k_ > c0) { tmp_ = c0; c0 = k_; k_ = tmp_; }                      \
        if (k_ > c1) { tmp_ = c1; c1 = k_; k_ = tmp_; }                      \
        if (k_ > c2) { tmp_ = c2; c2 = k_; k_ = tmp_; }                      \
        if (k_ > c3) { tmp_ = c3; c3 = k_; k_ = tmp_; }                      \
        if (k_ > c4) { tmp_ = c4; c4 = k_; k_ = tmp_; }                      \
        if (k_ > c5) { tmp_ = c5; c5 = k_; k_ = tmp_; }                      \
        if (k_ > c6) { tmp_ = c6; c6 = k_; k_ = tmp_; }                      \
        c7 = (k_ > c7) ? k_ : c7;                                            \
    }                                                                        \
} while (0)

// branch-free sorted-descending 8-float insert (fallback path only)
#define INSF(vv) do {                                                        \
    float x_ = (vv);                                                         \
    if (x_ > t7) {                                                           \
        float h_;                                                            \
        h_ = fmaxf(t0, x_); x_ = fminf(t0, x_); t0 = h_;                     \
        h_ = fmaxf(t1, x_); x_ = fminf(t1, x_); t1 = h_;                     \
        h_ = fmaxf(t2, x_); x_ = fminf(t2, x_); t2 = h_;                     \
        h_ = fmaxf(t3, x_); x_ = fminf(t3, x_); t3 = h_;                     \
        h_ = fmaxf(t4, x_); x_ = fminf(t4, x_); t4 = h_;                     \
        h_ = fmaxf(t5, x_); x_ = fminf(t5, x_); t5 = h_;                     \
        h_ = fmaxf(t6, x_); x_ = fminf(t6, x_); t6 = h_;                     \
        t7 = fmaxf(t7, x_);                                                  \
    }                                                                        \
} while (0)

#define COLLECT(v_) do {                                                     \
    if (v_.x >= T) { int p = atomicAdd(&s_n, 1); if (p < CAP) s_cand[p] = v_.x; } \
    if (v_.y >= T) { int p = atomicAdd(&s_n, 1); if (p < CAP) s_cand[p] = v_.y; } \
    if (v_.z >= T) { int p = atomicAdd(&s_n, 1); if (p < CAP) s_cand[p] = v_.z; } \
    if (v_.w >= T) { int p = atomicAdd(&s_n, 1); if (p < CAP) s_cand[p] = v_.w; } \
} while (0)

// ---- K1: DENSE fused copy-shape sweep: load f4, store zero f4, segment max ----
__global__ __launch_bounds__(256, 8)
void k1_sweep(const float* __restrict__ net_probs,
              float* __restrict__ out,
              float* __restrict__ ws)
{
    const int g = blockIdx.x * 256 + threadIdx.x;
    const int w = g >> 6;                        // global wave id (0..7999)
    const f4* np4 = (const f4*)net_probs;
    f4*       o4  = (f4*)out;
    const f4  z4  = (f4){0.f, 0.f, 0.f, 0.f};
    #pragma unroll 2
    for (int i = 0; i < ITER; ++i) {
        const size_t idx = (size_t)g + (size_t)i * NT_STREAM;
        f4 v = np4[idx];
        o4[idx] = z4;                            // same dense index: copy-shaped
        float m = MAX4(v);
        #pragma unroll
        for (int off = 32; off; off >>= 1) m = fmaxf(m, __shfl_xor(m, off));
        if ((threadIdx.x & 63) == 0) ws[w + i * NWAVE] = m;
    }
}

// ---------- K2: per-token threshold + selective re-read + math + scatter ----------
__global__ __launch_bounds__(256, 8)
void k2_final(const int*   __restrict__ tgt_index,
              const float* __restrict__ knn_dists,
              const float* __restrict__ knn_key,
              const float* __restrict__ net_probs,
              const float* __restrict__ net_sel,
              const float* __restrict__ W_func, const float* __restrict__ b_func,
              const float* __restrict__ W1a,    const float* __restrict__ b1a,
              const float* __restrict__ W1b,    const float* __restrict__ b1b,
              const float* __restrict__ W2a,    const float* __restrict__ b2a,
              const float* __restrict__ W2b,    const float* __restrict__ b2b,
              const float* __restrict__ ws,
              float* __restrict__ out)
{
    const int t   = blockIdx.x;
    const int tid = threadIdx.x;

    __shared__ float s_sm[128];     // 125 segment maxes (padded with 0)
    __shared__ int   s_qseg[128];
    __shared__ int   s_nq;
    __shared__ float s_thr;
    __shared__ float s_cand[CAP];
    __shared__ int   s_n;
    __shared__ float s_red[256];
    __shared__ int   s_win;
    __shared__ int   s_tgt[KNN];
    __shared__ float s_dist[KNN];
    __shared__ float s_cnt[KNN];
    __shared__ float s_top8[8];

    if (tid == 0) { s_nq = 0; s_n = 0; }

    int   tg = 0;
    float d = 0.f, lk = 0.f, ls = 0.f;
    if (tid < KNN) {
        tg = tgt_index[t * KNN + tid];
        d  = knn_dists[t * KNN + tid];
        lk = logf(knn_key[t * KNN + tid]);
        ls = logf(net_sel[t * KNN + tid]);
        s_tgt[tid]  = tg;
        s_dist[tid] = d;
    }
    if (tid < 128) s_sm[tid] = (tid < SEG_PER_TOK) ? ws[t * SEG_PER_TOK + tid] : 0.f;
    __syncthreads();

    // T = 8th largest segment max (one wave, 2 keys/lane over 128 slots)
    if (tid < 64) {
        ull c0 = 0, c1 = 0, c2 = 0, c3 = 0, c4 = 0, c5 = 0, c6 = 0, c7 = 0;
        ull k0 = (((ull)__float_as_uint(s_sm[tid])) << 32) | (unsigned)tid;
        INSK(k0);
        ull k1 = (((ull)__float_as_uint(s_sm[tid + 64])) << 32) | (unsigned)(tid + 64);
        INSK(k1);
        ull g = 0;
        for (int r = 0; r < 8; ++r) {
            g = c0;
            #pragma unroll
            for (int off = 1; off < 64; off <<= 1) {
                ull o = __shfl_xor(g, off);
                if (o > g) g = o;
            }
            if (c0 == g) {
                c0 = c1; c1 = c2; c2 = c3; c3 = c4; c4 = c5; c5 = c6; c6 = c7; c7 = 0;
            }
        }
        if (tid == 0) s_thr = __uint_as_float((unsigned)(g >> 32));
    }
    __syncthreads();
    const float T = s_thr;

    // qualifying segments (~8 of 125)
    if (tid < SEG_PER_TOK && s_sm[tid] >= T) {
        int p = atomicAdd(&s_nq, 1);
        s_qseg[p] = tid;
    }
    __syncthreads();
    const int nq = s_nq;

    // selective re-read: one wave per qualifying segment (64 f4 = 1 KB each)
    const f4* np4 = (const f4*)(net_probs + (size_t)t * VOCAB);
    for (int base = 0; base < nq; base += 4) {
        int qi = base + (tid >> 6);
        if (qi < nq) {
            int seg = s_qseg[qi];
            f4 v = np4[seg * 64 + (tid & 63)];
            COLLECT(v);
        }
    }
    __syncthreads();
    const int n = s_n;

    if (n <= CAP) {
        if (tid < 64) {
            ull c0 = 0, c1 = 0, c2 = 0, c3 = 0, c4 = 0, c5 = 0, c6 = 0, c7 = 0;
            for (int i = tid; i < n; i += 64) {
                ull key = (((ull)__float_as_uint(s_cand[i])) << 32) | (unsigned)i;
                INSK(key);
            }
            for (int r = 0; r < 8; ++r) {
                ull g = c0;
                #pragma unroll
                for (int off = 1; off < 64; off <<= 1) {
                    ull o = __shfl_xor(g, off);
                    if (o > g) g = o;
                }
                if (c0 == g && g != 0ULL) {
                    c0 = c1; c1 = c2; c2 = c3; c3 = c4; c4 = c5; c5 = c6; c6 = c7; c7 = 0;
                }
                if (tid == 0) s_top8[r] = __uint_as_float((unsigned)(g >> 32));
            }
        }
    } else {
        // fallback (adversarial ties): exact full-row per-thread top-8 + extraction
        float t0 = 0.f, t1 = 0.f, t2 = 0.f, t3 = 0.f,
              t4 = 0.f, t5 = 0.f, t6 = 0.f, t7 = 0.f;
        for (int k = 0; k < 31; ++k) {
            f4 v = np4[tid + (k << 8)];
            if (MAX4(v) > t7) { INSF(v.x); INSF(v.y); INSF(v.z); INSF(v.w); }
        }
        if (tid < 64) {
            f4 v = np4[tid + (31 << 8)];
            if (MAX4(v) > t7) { INSF(v.x); INSF(v.y); INSF(v.z); INSF(v.w); }
        }
        for (int r = 0; r < 8; ++r) {
            s_red[tid] = t0;
            __syncthreads();
            if (tid < 64) {
                float g = s_red[tid];
                g = fmaxf(g, s_red[tid + 64]);
                g = fmaxf(g, s_red[tid + 128]);
                g = fmaxf(g, s_red[tid + 192]);
                #pragma unroll
                for (int off = 1; off < 64; off <<= 1)
                    g = fmaxf(g, __shfl_xor(g, off));
                if (tid == 0) { s_thr = g; s_top8[r] = g; }
            }
            if (tid == 0) s_win = 0x7fffffff;
            __syncthreads();
            if (t0 == s_thr) atomicMin(&s_win, tid);
            __syncthreads();
            if (tid == s_win) {
                t0 = t1; t1 = t2; t2 = t3; t3 = t4; t4 = t5; t5 = t6; t6 = t7; t7 = 0.f;
            }
            __syncthreads();
        }
    }
    __syncthreads();

    // label counts (distinct, reference never counts label 0)
    if (tid < KNN) {
        int fo = (tg != 0) ? 1 : 0;
        if (fo) {
            for (int j = 0; j < tid; ++j)
                if (s_tgt[j] == tg) { fo = 0; break; }
        }
        int c = fo;
        #pragma unroll
        for (int off = 1; off < KNN; off <<= 1) {
            int n2 = __shfl_up(c, off, KNN);
            if (tid >= off) c += n2;
        }
        s_cnt[tid] = (float)c;
    }
    __syncthreads();

    if (tid < KNN) {
        // noise_logit: Linear(2,4) -> tanh -> Linear(4,1)
        float noise = b1b[0];
        #pragma unroll
        for (int j = 0; j < 4; ++j) {
            float z = tanhf(W1a[2 * j] * lk + W1a[2 * j + 1] * ls + b1a[j]);
            noise += W1b[j] * z;
        }

        // sim_lambda = W_func . [log(top8) | log_key | log_sel] + b_func
        float sp = W_func[8 + tid] * lk + W_func[40 + tid] * ls;
        if (tid < 8) sp += W_func[tid] * logf(s_top8[tid]);
        #pragma unroll
        for (int off = 16; off; off >>= 1) sp += __shfl_xor(sp, off, KNN);
        float sim = sp + b_func[0];

        // lambda_logit: Linear(64,32) -> tanh -> Linear(32,2); lane = hidden unit
        float h = b2a[tid];
        const float* wr = W2a + tid * 64;
        #pragma unroll 8
        for (int i = 0; i < KNN; ++i) h += wr[i] * s_dist[i];
        #pragma unroll 8
        for (int i = 0; i < KNN; ++i) h += wr[KNN + i] * s_cnt[i];
        h = tanhf(h);
        float p0 = W2b[tid] * h;
        float p1 = W2b[KNN + tid] * h;
        #pragma unroll
        for (int off = 16; off; off >>= 1) {
            p0 += __shfl_xor(p0, off, KNN);
            p1 += __shfl_xor(p1, off, KNN);
        }
        float l0 = p0 + b2b[0];
        float l1 = p1 + b2b[1];

        float tempe = 1.f / (1.f + expf(-l1));          // sigmoid(l1)
        float lam   = 1.f / (1.f + expf(-(l0 - sim)));  // softmax([l0,sim])[0]

        // probs = softmax(-d*tempe + noise) over K
        float logit = -d * tempe + noise;
        float mx = logit;
        #pragma unroll
        for (int off = 16; off; off >>= 1) mx = fmaxf(mx, __shfl_xor(mx, off, KNN));
        float e = expf(logit - mx);
        float se = e;
        #pragma unroll
        for (int off = 16; off; off >>= 1) se += __shfl_xor(se, off, KNN);
        float p = e / se;

        // scatter, last-occurrence-wins on duplicate indices (numpy semantics)
        bool wrte = true;
        for (int j = tid + 1; j < KNN; ++j)
            if (s_tgt[j] == tg) { wrte = false; break; }
        if (wrte) out[(size_t)t * VOCAB + tg] = p;

        if (tid == 0) out[(size_t)TOKENS * VOCAB + t] = lam;
    }
}

extern "C" void kernel_launch(void* const* d_in, const int* in_sizes, int n_in,
                              void* d_out, int out_size, void* d_ws, size_t ws_size,
                              hipStream_t stream) {
    float* ws = (float*)d_ws;   // 256,000 floats = 1 MB

    // fused dense copy-shape sweep: read row + zero output + segment maxes
    k1_sweep<<<NB_STREAM, 256, 0, stream>>>(
        (const float*)d_in[3], (float*)d_out, ws);
    // per-token epilogue
    k2_final<<<TOKENS, 256, 0, stream>>>(
        (const int*)  d_in[0],   // tgt_index
        (const float*)d_in[1],   // knn_dists
        (const float*)d_in[2],   // knn_key_feature
        (const float*)d_in[3],   // network_probs
        (const float*)d_in[4],   // network_select_probs
        (const float*)d_in[5],  (const float*)d_in[6],   // W_func, b_func
        (const float*)d_in[7],  (const float*)d_in[8],   // W1a, b1a
        (const float*)d_in[9],  (const float*)d_in[10],  // W1b, b1b
        (const float*)d_in[11], (const float*)d_in[12],  // W2a, b2a
        (const float*)d_in[13], (const float*)d_in[14],  // W2b, b2b
        ws,
        (float*)d_out);
}